// Round 11
// baseline (236.362 us; speedup 1.0000x reference)
//
#include <hip/hip_runtime.h>

#define B_TOTAL 32768
#define NATOM   512
#define MDIM    64
#define KS      5

// ---------------------------------------------------------------------------
// K_GRAM: G = D^T D (512 blocks). Zeroes acc[0] (loss) and acc[1] (counter).
// ---------------------------------------------------------------------------
__global__ void k_gram(const float* __restrict__ D, float* __restrict__ G,
                       float* __restrict__ acc) {
    const int i = blockIdx.x;
    const int t = threadIdx.x;
    __shared__ float col[MDIM];
    if (t < MDIM) col[t] = D[t * NATOM + i];
    __syncthreads();
    for (int j = t; j < NATOM; j += 256) {
        float s = 0.f;
#pragma unroll
        for (int m = 0; m < MDIM; ++m) s = fmaf(col[m], D[m * NATOM + j], s);
        G[i * NATOM + j] = s;
    }
    if (i == 0 && t == 0) { acc[0] = 0.f; ((unsigned*)acc)[1] = 0u; }
}

// ---------------------------------------------------------------------------
// K2: fused h_bar GEMM + per-column OMP — R9's proven 75.1us body with a
// REMAPPED block->b assignment so direct-z_e staging is coalesced:
// R10 post-mortem: old mapping (block = 32 consecutive b = 32 c values at
// ONE w) makes the z_e tile a pure 3D gather (64B line per 4B used, FETCH
// 9->21MB, k_omp 75->134us). Fix: block = (hf, c), local bb = w 0..31:
//   b(bb) = (hf<<11) | (bb<<6) | c
// Then the tile is 64 contiguous 128B runs in z_e:
//   ze[(m>>1)*65536 + c*1024 + ((m&1)<<9) + hf*32 + bb]
// (consecutive t -> consecutive bb -> coalesced). OMP is per-b independent,
// so per-b arithmetic is bitwise identical to R9; only the output addresses
// change (5x32 scattered 4B stores per block — negligible).
// ---------------------------------------------------------------------------
__launch_bounds__(256, 2)
__global__ void k_omp(const float* __restrict__ ze, const float* __restrict__ D,
                      const float* __restrict__ G, int* __restrict__ idx_out,
                      float* __restrict__ val_out) {
    const int t    = threadIdx.x;
    const int lane = t & 63;
    const int wv   = t >> 6;
    const int cix  = blockIdx.x & 63;      // c (channel) for this block
    const int hf   = blockIdx.x >> 6;      // h&15 for this block
    const int bbase = (hf << 11) | cix;    // b = bbase + bb*64, bb = w

    __shared__ __align__(16) float data_s[32][68];
    __shared__ __align__(16) float stage[4][2048];   // 8KB per wave

    // stage data tile (64 m x 32 bb=w), coalesced: consecutive t -> bb
    {
        const int cbase = cix * 1024 + hf * 32;
#pragma unroll
        for (int r = 0; r < 8; ++r) {
            int id = r * 256 + t;
            int m = id >> 5, bb = id & 31;
            data_s[bb][m] =
                ze[(m >> 1) * 65536 + cbase + ((m & 1) << 9) + bb];
        }
    }
    __syncthreads();

    const float4* __restrict__ D4 = (const float4*)D;
    const float4* __restrict__ G4 = (const float4*)G;

    // ---- phase 1: h_bar accumulators, 8 b x 8 atoms per lane ----
    float4 acc[8][2];
#pragma unroll
    for (int bb = 0; bb < 8; ++bb) {
        acc[bb][0] = make_float4(0.f, 0.f, 0.f, 0.f);
        acc[bb][1] = make_float4(0.f, 0.f, 0.f, 0.f);
    }
    const int bwbase = wv * 8;

#pragma unroll 4
    for (int c = 0; c < 16; ++c) {
        float4 df[4][2];
#pragma unroll
        for (int mm = 0; mm < 4; ++mm) {
            df[mm][0] = D4[(c * 4 + mm) * 128 + lane];
            df[mm][1] = D4[(c * 4 + mm) * 128 + 64 + lane];
        }
#pragma unroll
        for (int bb = 0; bb < 8; ++bb) {
            const float4 dv = *(const float4*)&data_s[bwbase + bb][c * 4];
            const float dm[4] = {dv.x, dv.y, dv.z, dv.w};
#pragma unroll
            for (int mm = 0; mm < 4; ++mm) {
                acc[bb][0].x = fmaf(df[mm][0].x, dm[mm], acc[bb][0].x);
                acc[bb][0].y = fmaf(df[mm][0].y, dm[mm], acc[bb][0].y);
                acc[bb][0].z = fmaf(df[mm][0].z, dm[mm], acc[bb][0].z);
                acc[bb][0].w = fmaf(df[mm][0].w, dm[mm], acc[bb][0].w);
                acc[bb][1].x = fmaf(df[mm][1].x, dm[mm], acc[bb][1].x);
                acc[bb][1].y = fmaf(df[mm][1].y, dm[mm], acc[bb][1].y);
                acc[bb][1].z = fmaf(df[mm][1].z, dm[mm], acc[bb][1].z);
                acc[bb][1].w = fmaf(df[mm][1].w, dm[mm], acc[bb][1].w);
            }
        }
    }

    // ---- re-stage: acc(8b x 8 atoms) -> hb(64 atoms of group's b) ----
    // 2 rounds of 4 b through the 8KB/wave stage (R0 scheme, verbatim).
    const int g = lane >> 3;       // group = b within wave's 8
    const int p = lane & 7;        // lane within group
    float hb[64];
#pragma unroll
    for (int r = 0; r < 2; ++r) {
        __syncthreads();           // round r-1 reads complete before overwrite
#pragma unroll
        for (int q2 = 0; q2 < 4; ++q2) {
            int bb = r * 4 + q2;
            *(float4*)&stage[wv][q2 * 512 + 4 * lane]       = acc[bb][0];
            *(float4*)&stage[wv][q2 * 512 + 256 + 4 * lane] = acc[bb][1];
        }
        __syncthreads();           // writes committed before reads
        if ((g >> 2) == r) {
#pragma unroll
            for (int q = 0; q < 16; ++q) {
                const float4 v =
                    *(const float4*)&stage[wv][(g & 3) * 512 + 32 * q + 4 * p];
                hb[4 * q + 0] = v.x;
                hb[4 * q + 1] = v.y;
                hb[4 * q + 2] = v.z;
                hb[4 * q + 3] = v.w;
            }
        }
    }

    // ---- phase 2: OMP, 8 concurrent b (one per 8-lane group) ----
    float key[64];
#pragma unroll
    for (int e = 0; e < 64; ++e) key[e] = fabsf(hb[e]);

    unsigned msk0 = 0u, msk1 = 0u;
    int   I[KS];
    float xs[KS];
    float gsel[KS];
    float Lm[15];                   // packed lower-tri

#pragma unroll
    for (int k = 0; k < KS; ++k) {
        // --- 4-way ILP argmax over 64 register keys (mask pre-folded -1) ---
        float cv[4]; int ce[4]; float ch[4];
#pragma unroll
        for (int c4 = 0; c4 < 4; ++c4) {
            cv[c4] = key[16 * c4]; ce[c4] = 16 * c4; ch[c4] = hb[16 * c4];
#pragma unroll
            for (int e = 16 * c4 + 1; e < 16 * c4 + 16; ++e) {
                bool gt = key[e] > cv[c4];  // strict > keeps lowest e
                cv[c4] = gt ? key[e] : cv[c4];
                ce[c4] = gt ? e      : ce[c4];
                ch[c4] = gt ? hb[e]  : ch[c4];
            }
        }
        // combine chains in ascending-e order; strict > keeps lower chain
        float bv = cv[0]; int be = ce[0]; float bhb = ch[0];
#pragma unroll
        for (int c4 = 1; c4 < 4; ++c4) {
            bool gt = cv[c4] > bv;
            bv  = gt ? cv[c4] : bv;
            be  = gt ? ce[c4] : be;
            bhb = gt ? ch[c4] : bhb;
        }
        int bn = 32 * (be >> 2) + 4 * p + (be & 3);
        // --- 3-step reduce across the 8-lane group ---
#pragma unroll
        for (int off = 1; off < 8; off <<= 1) {
            float ov  = __shfl_xor(bv, off);
            int   on  = __shfl_xor(bn, off);
            float ohb = __shfl_xor(bhb, off);
            bool take = (ov > bv) || (ov == bv && on < bn);
            bv = take ? ov : bv; bn = take ? on : bn; bhb = take ? ohb : bhb;
        }
        const int nsel = bn;                // group-uniform
        I[k]    = nsel;
        gsel[k] = bhb;                      // = h_bar[nsel] (original), exact

        // mask the selected atom for future scans
        {
            int own  = (nsel >> 2) & 7;
            int esel = ((nsel >> 5) << 2) | (nsel & 3);
            if (p == own) {
                if (esel < 32) msk0 |= 1u << esel;
                else           msk1 |= 1u << (esel - 32);
            }
        }

        // --- Cholesky update of L ---
        if (k > 0) {
            float gk[KS - 1], w[KS - 1];
#pragma unroll
            for (int ti = 0; ti < KS - 1; ++ti)
                if (ti < k) gk[ti] = G[I[ti] * NATOM + nsel];
#pragma unroll
            for (int r = 0; r < KS - 1; ++r) {
                if (r < k) {
                    float s = gk[r];
#pragma unroll
                    for (int cc = 0; cc < KS - 1; ++cc)
                        if (cc < r) s -= Lm[r * (r + 1) / 2 + cc] * w[cc];
                    w[r] = s / Lm[r * (r + 1) / 2 + r];
                }
            }
            float s2 = 0.f;
#pragma unroll
            for (int r = 0; r < KS - 1; ++r) if (r < k) s2 += w[r] * w[r];
            float wc = sqrtf(fmaxf(0.f, 1.f - s2));
#pragma unroll
            for (int cc = 0; cc < KS - 1; ++cc)
                if (cc < k) Lm[k * (k + 1) / 2 + cc] = w[cc];
            Lm[k * (k + 1) / 2 + k] = wc;
        } else {
            Lm[0] = 1.f;
        }

        // --- solve L y = gsel ; L^T x = y (replicated within group) ---
        float y[KS];
#pragma unroll
        for (int r = 0; r <= k; ++r) {
            float s = gsel[r];
#pragma unroll
            for (int cc = 0; cc < r; ++cc) s -= Lm[r * (r + 1) / 2 + cc] * y[cc];
            y[r] = s / Lm[r * (r + 1) / 2 + r];
        }
#pragma unroll
        for (int r = k; r >= 0; --r) {
            float s = y[r];
#pragma unroll
            for (int cc = r + 1; cc <= k; ++cc) s -= Lm[cc * (cc + 1) / 2 + r] * xs[cc];
            xs[r] = s / Lm[r * (r + 1) / 2 + r];
        }

        // --- fused beta + key update (no beta[] array; ascending-ti fma) ---
        if (k < KS - 1) {
#pragma unroll
            for (int q = 0; q < 16; ++q) {
                float bx = 0.f, by = 0.f, bz = 0.f, bw = 0.f;
#pragma unroll
                for (int ti = 0; ti < KS - 1; ++ti) {
                    if (ti <= k) {
                        const float4 gc = G4[I[ti] * 128 + 8 * q + p];
                        bx = fmaf(xs[ti], gc.x, bx);
                        by = fmaf(xs[ti], gc.y, by);
                        bz = fmaf(xs[ti], gc.z, bz);
                        bw = fmaf(xs[ti], gc.w, bw);
                    }
                }
                {
                    float d0 = hb[4 * q + 0] - bx;
                    float d1 = hb[4 * q + 1] - by;
                    float d2 = hb[4 * q + 2] - bz;
                    float d3 = hb[4 * q + 3] - bw;
                    const int e0 = 4 * q;
                    bool m0 = (e0 + 0 < 32) ? ((msk0 >> (e0 + 0)) & 1u) : ((msk1 >> (e0 - 32)) & 1u);
                    bool m1 = (e0 + 1 < 32) ? ((msk0 >> (e0 + 1)) & 1u) : ((msk1 >> (e0 + 1 - 32)) & 1u);
                    bool m2 = (e0 + 2 < 32) ? ((msk0 >> (e0 + 2)) & 1u) : ((msk1 >> (e0 + 2 - 32)) & 1u);
                    bool m3 = (e0 + 3 < 32) ? ((msk0 >> (e0 + 3)) & 1u) : ((msk1 >> (e0 + 3 - 32)) & 1u);
                    key[e0 + 0] = m0 ? -1.f : fabsf(d0);
                    key[e0 + 1] = m1 ? -1.f : fabsf(d1);
                    key[e0 + 2] = m2 ? -1.f : fabsf(d2);
                    key[e0 + 3] = m3 ? -1.f : fabsf(d3);
                }
            }
        }
    }

    // outputs: one lane per b; b = bbase + (wv*8+g)*64 (scattered 4B stores)
    if (p == 0) {
        const int b = bbase + ((wv * 8 + g) << 6);
#pragma unroll
        for (int k = 0; k < KS; ++k) {
            idx_out[k * B_TOTAL + b] = I[k];
            val_out[k * B_TOTAL + b] = xs[k];
        }
    }
}

// ---------------------------------------------------------------------------
// K_POST: fused coeff (blocks 0..1023) + recon (blocks 1024..1535) + loss
// finalize (done-counter, harness-proven in R7/R10).
// Recon rewritten j-major: compute order == z_e order, so ze reads AND zout
// writes are coalesced and the LDS transpose + barrier disappear (same
// thread computes and stores). idx/val become stride-64 gathers into a
// 1.25MB L2-resident array — cheap side of the trade (R10 post-mortem).
// ---------------------------------------------------------------------------
__global__ void k_post(const int* __restrict__ idx, const float* __restrict__ val,
                       float* __restrict__ coeff, const float* __restrict__ ze,
                       const float* __restrict__ D, float* __restrict__ zout,
                       float* __restrict__ acc, float* __restrict__ out_loss) {
    const int t = threadIdx.x;
    if (blockIdx.x < 1024) {
        const int bblk = blockIdx.x >> 3;
        const int jc   = blockIdx.x & 7;
        const int b    = bblk * 256 + t;
        int   I[KS]; float V[KS];
#pragma unroll
        for (int k = 0; k < KS; ++k) {
            I[k] = idx[k * B_TOTAL + b];
            V[k] = val[k * B_TOTAL + b];
        }
        const int j0 = jc * 64;
#pragma unroll 4
        for (int j = j0; j < j0 + 64; ++j) {
            float w = 0.f;
#pragma unroll
            for (int k = 0; k < KS; ++k) w = (I[k] == j) ? V[k] : w;
            coeff[j * B_TOTAL + b] = w;
        }
    } else {
        const int blk = blockIdx.x - 1024;
        const int n   = blk >> 4;
        const int hw0 = (blk & 15) * 64;
        float sq = 0.f;
#pragma unroll
        for (int r = 0; r < 16; ++r) {
            int id = r * 256 + t;
            int j = id & 63;           // hw offset: consecutive t -> coalesced
            int c = id >> 6;           // channel
            int f = n * 65536 + (hw0 + j) * 64 + c;   // z_perm flat index
            int b = f & 32767;
            int m = f >> 15;
            float zdl = 0.f;
#pragma unroll
            for (int k = 0; k < KS; ++k) {
                int   a = idx[k * B_TOTAL + b];
                float v = val[k * B_TOTAL + b];
                zdl = fmaf(v, D[m * NATOM + a], zdl);
            }
            const int za = n * 65536 + c * 1024 + hw0 + j;
            float zp   = ze[za];
            float diff = zdl - zp;
            zout[za] = zp + diff;
            sq = fmaf(diff, diff, sq);
        }
#pragma unroll
        for (int off = 32; off > 0; off >>= 1) sq += __shfl_xor(sq, off);
        __shared__ float red[4];
        if ((t & 63) == 0) red[t >> 6] = sq;
        __syncthreads();
        if (t == 0) {
            atomicAdd(acc, red[0] + red[1] + red[2] + red[3]);
            __threadfence();
            unsigned prev = atomicAdd(((unsigned*)acc) + 1, 1u);
            if (prev == 511u) {            // last recon block: all adds visible
                float a = atomicAdd(acc, 0.f);   // device-coherent read
                out_loss[0] = 1.25f * (a / 2097152.f);
            }
        }
    }
}

// ---------------------------------------------------------------------------
extern "C" void kernel_launch(void* const* d_in, const int* in_sizes, int n_in,
                              void* d_out, int out_size, void* d_ws, size_t ws_size,
                              hipStream_t stream) {
    const float* ze = (const float*)d_in[0];
    const float* D  = (const float*)d_in[1];

    float* G     = (float*)d_ws;
    int*   idxp  = (int*)  ((char*)d_ws + (size_t)262144 * 4);
    float* valp  = (float*)((char*)d_ws + (size_t)(262144 + 163840) * 4);
    float* accp  = (float*)((char*)d_ws + (size_t)(262144 + 2 * 163840) * 4);

    float* zout  = (float*)d_out;
    float* lossp = zout + 2097152;
    float* coeff = zout + 2097153;

    k_gram<<< 512, 256, 0, stream>>>(D, G, accp);
    k_omp <<<1024, 256, 0, stream>>>(ze, D, G, idxp, valp);
    k_post<<<1536, 256, 0, stream>>>(idxp, valp, coeff, ze, D, zout, accp, lossp);
}

// Round 12
// 193.525 us; speedup vs baseline: 1.2214x; 1.2214x over previous
//
#include <hip/hip_runtime.h>

#define B_TOTAL 32768
#define NATOM   512
#define MDIM    64
#define KS      5

// ---------------------------------------------------------------------------
// K_GRAM: G = D^T D (512 blocks). Zeroes acc[0] (loss) and acc[1] (counter).
// ---------------------------------------------------------------------------
__global__ void k_gram(const float* __restrict__ D, float* __restrict__ G,
                       float* __restrict__ acc) {
    const int i = blockIdx.x;
    const int t = threadIdx.x;
    __shared__ float col[MDIM];
    if (t < MDIM) col[t] = D[t * NATOM + i];
    __syncthreads();
    for (int j = t; j < NATOM; j += 256) {
        float s = 0.f;
#pragma unroll
        for (int m = 0; m < MDIM; ++m) s = fmaf(col[m], D[m * NATOM + j], s);
        G[i * NATOM + j] = s;
    }
    if (i == 0 && t == 0) { acc[0] = 0.f; ((unsigned*)acc)[1] = 0u; }
}

// ---------------------------------------------------------------------------
// K2: fused h_bar GEMM + per-column OMP — R11's kernel VERBATIM (the (hf,c)
// block->b remap made direct-z_e staging coalesced and removed k_omp from
// the top-5: <=87us vs R10's 133.6).
//   block = (hf, c); b(bb) = (hf<<11) | (bb<<6) | c, bb = w = 0..31
//   tile read: ze[(m>>1)*65536 + c*1024 + ((m&1)<<9) + hf*32 + bb]
// ---------------------------------------------------------------------------
__launch_bounds__(256, 2)
__global__ void k_omp(const float* __restrict__ ze, const float* __restrict__ D,
                      const float* __restrict__ G, int* __restrict__ idx_out,
                      float* __restrict__ val_out) {
    const int t    = threadIdx.x;
    const int lane = t & 63;
    const int wv   = t >> 6;
    const int cix  = blockIdx.x & 63;      // c (channel) for this block
    const int hf   = blockIdx.x >> 6;      // h&15 for this block
    const int bbase = (hf << 11) | cix;    // b = bbase + bb*64, bb = w

    __shared__ __align__(16) float data_s[32][68];
    __shared__ __align__(16) float stage[4][2048];   // 8KB per wave

    // stage data tile (64 m x 32 bb=w), coalesced: consecutive t -> bb
    {
        const int cbase = cix * 1024 + hf * 32;
#pragma unroll
        for (int r = 0; r < 8; ++r) {
            int id = r * 256 + t;
            int m = id >> 5, bb = id & 31;
            data_s[bb][m] =
                ze[(m >> 1) * 65536 + cbase + ((m & 1) << 9) + bb];
        }
    }
    __syncthreads();

    const float4* __restrict__ D4 = (const float4*)D;
    const float4* __restrict__ G4 = (const float4*)G;

    // ---- phase 1: h_bar accumulators, 8 b x 8 atoms per lane ----
    float4 acc[8][2];
#pragma unroll
    for (int bb = 0; bb < 8; ++bb) {
        acc[bb][0] = make_float4(0.f, 0.f, 0.f, 0.f);
        acc[bb][1] = make_float4(0.f, 0.f, 0.f, 0.f);
    }
    const int bwbase = wv * 8;

#pragma unroll 4
    for (int c = 0; c < 16; ++c) {
        float4 df[4][2];
#pragma unroll
        for (int mm = 0; mm < 4; ++mm) {
            df[mm][0] = D4[(c * 4 + mm) * 128 + lane];
            df[mm][1] = D4[(c * 4 + mm) * 128 + 64 + lane];
        }
#pragma unroll
        for (int bb = 0; bb < 8; ++bb) {
            const float4 dv = *(const float4*)&data_s[bwbase + bb][c * 4];
            const float dm[4] = {dv.x, dv.y, dv.z, dv.w};
#pragma unroll
            for (int mm = 0; mm < 4; ++mm) {
                acc[bb][0].x = fmaf(df[mm][0].x, dm[mm], acc[bb][0].x);
                acc[bb][0].y = fmaf(df[mm][0].y, dm[mm], acc[bb][0].y);
                acc[bb][0].z = fmaf(df[mm][0].z, dm[mm], acc[bb][0].z);
                acc[bb][0].w = fmaf(df[mm][0].w, dm[mm], acc[bb][0].w);
                acc[bb][1].x = fmaf(df[mm][1].x, dm[mm], acc[bb][1].x);
                acc[bb][1].y = fmaf(df[mm][1].y, dm[mm], acc[bb][1].y);
                acc[bb][1].z = fmaf(df[mm][1].z, dm[mm], acc[bb][1].z);
                acc[bb][1].w = fmaf(df[mm][1].w, dm[mm], acc[bb][1].w);
            }
        }
    }

    // ---- re-stage: acc(8b x 8 atoms) -> hb(64 atoms of group's b) ----
    // 2 rounds of 4 b through the 8KB/wave stage (R0 scheme, verbatim).
    const int g = lane >> 3;       // group = b within wave's 8
    const int p = lane & 7;        // lane within group
    float hb[64];
#pragma unroll
    for (int r = 0; r < 2; ++r) {
        __syncthreads();           // round r-1 reads complete before overwrite
#pragma unroll
        for (int q2 = 0; q2 < 4; ++q2) {
            int bb = r * 4 + q2;
            *(float4*)&stage[wv][q2 * 512 + 4 * lane]       = acc[bb][0];
            *(float4*)&stage[wv][q2 * 512 + 256 + 4 * lane] = acc[bb][1];
        }
        __syncthreads();           // writes committed before reads
        if ((g >> 2) == r) {
#pragma unroll
            for (int q = 0; q < 16; ++q) {
                const float4 v =
                    *(const float4*)&stage[wv][(g & 3) * 512 + 32 * q + 4 * p];
                hb[4 * q + 0] = v.x;
                hb[4 * q + 1] = v.y;
                hb[4 * q + 2] = v.z;
                hb[4 * q + 3] = v.w;
            }
        }
    }

    // ---- phase 2: OMP, 8 concurrent b (one per 8-lane group) ----
    float key[64];
#pragma unroll
    for (int e = 0; e < 64; ++e) key[e] = fabsf(hb[e]);

    unsigned msk0 = 0u, msk1 = 0u;
    int   I[KS];
    float xs[KS];
    float gsel[KS];
    float Lm[15];                   // packed lower-tri

#pragma unroll
    for (int k = 0; k < KS; ++k) {
        // --- 4-way ILP argmax over 64 register keys (mask pre-folded -1) ---
        float cv[4]; int ce[4]; float ch[4];
#pragma unroll
        for (int c4 = 0; c4 < 4; ++c4) {
            cv[c4] = key[16 * c4]; ce[c4] = 16 * c4; ch[c4] = hb[16 * c4];
#pragma unroll
            for (int e = 16 * c4 + 1; e < 16 * c4 + 16; ++e) {
                bool gt = key[e] > cv[c4];  // strict > keeps lowest e
                cv[c4] = gt ? key[e] : cv[c4];
                ce[c4] = gt ? e      : ce[c4];
                ch[c4] = gt ? hb[e]  : ch[c4];
            }
        }
        // combine chains in ascending-e order; strict > keeps lower chain
        float bv = cv[0]; int be = ce[0]; float bhb = ch[0];
#pragma unroll
        for (int c4 = 1; c4 < 4; ++c4) {
            bool gt = cv[c4] > bv;
            bv  = gt ? cv[c4] : bv;
            be  = gt ? ce[c4] : be;
            bhb = gt ? ch[c4] : bhb;
        }
        int bn = 32 * (be >> 2) + 4 * p + (be & 3);
        // --- 3-step reduce across the 8-lane group ---
#pragma unroll
        for (int off = 1; off < 8; off <<= 1) {
            float ov  = __shfl_xor(bv, off);
            int   on  = __shfl_xor(bn, off);
            float ohb = __shfl_xor(bhb, off);
            bool take = (ov > bv) || (ov == bv && on < bn);
            bv = take ? ov : bv; bn = take ? on : bn; bhb = take ? ohb : bhb;
        }
        const int nsel = bn;                // group-uniform
        I[k]    = nsel;
        gsel[k] = bhb;                      // = h_bar[nsel] (original), exact

        // mask the selected atom for future scans
        {
            int own  = (nsel >> 2) & 7;
            int esel = ((nsel >> 5) << 2) | (nsel & 3);
            if (p == own) {
                if (esel < 32) msk0 |= 1u << esel;
                else           msk1 |= 1u << (esel - 32);
            }
        }

        // --- Cholesky update of L ---
        if (k > 0) {
            float gk[KS - 1], w[KS - 1];
#pragma unroll
            for (int ti = 0; ti < KS - 1; ++ti)
                if (ti < k) gk[ti] = G[I[ti] * NATOM + nsel];
#pragma unroll
            for (int r = 0; r < KS - 1; ++r) {
                if (r < k) {
                    float s = gk[r];
#pragma unroll
                    for (int cc = 0; cc < KS - 1; ++cc)
                        if (cc < r) s -= Lm[r * (r + 1) / 2 + cc] * w[cc];
                    w[r] = s / Lm[r * (r + 1) / 2 + r];
                }
            }
            float s2 = 0.f;
#pragma unroll
            for (int r = 0; r < KS - 1; ++r) if (r < k) s2 += w[r] * w[r];
            float wc = sqrtf(fmaxf(0.f, 1.f - s2));
#pragma unroll
            for (int cc = 0; cc < KS - 1; ++cc)
                if (cc < k) Lm[k * (k + 1) / 2 + cc] = w[cc];
            Lm[k * (k + 1) / 2 + k] = wc;
        } else {
            Lm[0] = 1.f;
        }

        // --- solve L y = gsel ; L^T x = y (replicated within group) ---
        float y[KS];
#pragma unroll
        for (int r = 0; r <= k; ++r) {
            float s = gsel[r];
#pragma unroll
            for (int cc = 0; cc < r; ++cc) s -= Lm[r * (r + 1) / 2 + cc] * y[cc];
            y[r] = s / Lm[r * (r + 1) / 2 + r];
        }
#pragma unroll
        for (int r = k; r >= 0; --r) {
            float s = y[r];
#pragma unroll
            for (int cc = r + 1; cc <= k; ++cc) s -= Lm[cc * (cc + 1) / 2 + r] * xs[cc];
            xs[r] = s / Lm[r * (r + 1) / 2 + r];
        }

        // --- fused beta + key update (no beta[] array; ascending-ti fma) ---
        if (k < KS - 1) {
#pragma unroll
            for (int q = 0; q < 16; ++q) {
                float bx = 0.f, by = 0.f, bz = 0.f, bw = 0.f;
#pragma unroll
                for (int ti = 0; ti < KS - 1; ++ti) {
                    if (ti <= k) {
                        const float4 gc = G4[I[ti] * 128 + 8 * q + p];
                        bx = fmaf(xs[ti], gc.x, bx);
                        by = fmaf(xs[ti], gc.y, by);
                        bz = fmaf(xs[ti], gc.z, bz);
                        bw = fmaf(xs[ti], gc.w, bw);
                    }
                }
                {
                    float d0 = hb[4 * q + 0] - bx;
                    float d1 = hb[4 * q + 1] - by;
                    float d2 = hb[4 * q + 2] - bz;
                    float d3 = hb[4 * q + 3] - bw;
                    const int e0 = 4 * q;
                    bool m0 = (e0 + 0 < 32) ? ((msk0 >> (e0 + 0)) & 1u) : ((msk1 >> (e0 - 32)) & 1u);
                    bool m1 = (e0 + 1 < 32) ? ((msk0 >> (e0 + 1)) & 1u) : ((msk1 >> (e0 + 1 - 32)) & 1u);
                    bool m2 = (e0 + 2 < 32) ? ((msk0 >> (e0 + 2)) & 1u) : ((msk1 >> (e0 + 2 - 32)) & 1u);
                    bool m3 = (e0 + 3 < 32) ? ((msk0 >> (e0 + 3)) & 1u) : ((msk1 >> (e0 + 3 - 32)) & 1u);
                    key[e0 + 0] = m0 ? -1.f : fabsf(d0);
                    key[e0 + 1] = m1 ? -1.f : fabsf(d1);
                    key[e0 + 2] = m2 ? -1.f : fabsf(d2);
                    key[e0 + 3] = m3 ? -1.f : fabsf(d3);
                }
            }
        }
    }

    // outputs: one lane per b; b = bbase + (wv*8+g)*64 (scattered 4B stores)
    if (p == 0) {
        const int b = bbase + ((wv * 8 + g) << 6);
#pragma unroll
        for (int k = 0; k < KS; ++k) {
            idx_out[k * B_TOTAL + b] = I[k];
            val_out[k * B_TOTAL + b] = xs[k];
        }
    }
}

// ---------------------------------------------------------------------------
// K_POST: R10's version VERBATIM — fused coeff (blocks 0..1023) + c-major
// recon (blocks 1024..1535) + done-counter loss finalize.
// R11 post-mortem: gather cost scales with ACCESSES PER THREAD. c-major
// recon gathers ze (16/thread, L2-absorbed: R10 post ~45us) and keeps
// idx/val (80 accesses/thread) + zout coalesced. R11's j-major flipped
// that trade and cost +43us.
// ---------------------------------------------------------------------------
__global__ void k_post(const int* __restrict__ idx, const float* __restrict__ val,
                       float* __restrict__ coeff, const float* __restrict__ ze,
                       const float* __restrict__ D, float* __restrict__ zout,
                       float* __restrict__ acc, float* __restrict__ out_loss) {
    __shared__ float lds[64][65];
    const int t = threadIdx.x;
    if (blockIdx.x < 1024) {
        const int bblk = blockIdx.x >> 3;
        const int jc   = blockIdx.x & 7;
        const int b    = bblk * 256 + t;
        int   I[KS]; float V[KS];
#pragma unroll
        for (int k = 0; k < KS; ++k) {
            I[k] = idx[k * B_TOTAL + b];
            V[k] = val[k * B_TOTAL + b];
        }
        const int j0 = jc * 64;
#pragma unroll 4
        for (int j = j0; j < j0 + 64; ++j) {
            float w = 0.f;
#pragma unroll
            for (int k = 0; k < KS; ++k) w = (I[k] == j) ? V[k] : w;
            coeff[j * B_TOTAL + b] = w;
        }
    } else {
        const int blk = blockIdx.x - 1024;
        const int n   = blk >> 4;
        const int hw0 = (blk & 15) * 64;
        float sq = 0.f;
#pragma unroll
        for (int r = 0; r < 16; ++r) {
            int id = r * 256 + t;
            int c = id & 63, j = id >> 6;
            int f = n * 65536 + (hw0 + j) * 64 + c;
            int b = f & 32767;
            int m = f >> 15;
            float zdl = 0.f;
#pragma unroll
            for (int k = 0; k < KS; ++k) {
                int   a = idx[k * B_TOTAL + b];
                float v = val[k * B_TOTAL + b];
                zdl = fmaf(v, D[m * NATOM + a], zdl);
            }
            float zp   = ze[n * 65536 + c * 1024 + hw0 + j];  // direct z_e read
            float diff = zdl - zp;
            lds[c][j] = zp + diff;
            sq = fmaf(diff, diff, sq);
        }
        __syncthreads();
#pragma unroll
        for (int r = 0; r < 16; ++r) {
            int id = r * 256 + t;
            int cc = id >> 6, i = id & 63;
            zout[n * 65536 + cc * 1024 + hw0 + i] = lds[cc][i];
        }
#pragma unroll
        for (int off = 32; off > 0; off >>= 1) sq += __shfl_xor(sq, off);
        __shared__ float red[4];
        if ((t & 63) == 0) red[t >> 6] = sq;
        __syncthreads();
        if (t == 0) {
            atomicAdd(acc, red[0] + red[1] + red[2] + red[3]);
            __threadfence();
            unsigned prev = atomicAdd(((unsigned*)acc) + 1, 1u);
            if (prev == 511u) {            // last recon block: all adds visible
                float a = atomicAdd(acc, 0.f);   // device-coherent read
                out_loss[0] = 1.25f * (a / 2097152.f);
            }
        }
    }
}

// ---------------------------------------------------------------------------
extern "C" void kernel_launch(void* const* d_in, const int* in_sizes, int n_in,
                              void* d_out, int out_size, void* d_ws, size_t ws_size,
                              hipStream_t stream) {
    const float* ze = (const float*)d_in[0];
    const float* D  = (const float*)d_in[1];

    float* G     = (float*)d_ws;
    int*   idxp  = (int*)  ((char*)d_ws + (size_t)262144 * 4);
    float* valp  = (float*)((char*)d_ws + (size_t)(262144 + 163840) * 4);
    float* accp  = (float*)((char*)d_ws + (size_t)(262144 + 2 * 163840) * 4);

    float* zout  = (float*)d_out;
    float* lossp = zout + 2097152;
    float* coeff = zout + 2097153;

    k_gram<<< 512, 256, 0, stream>>>(D, G, accp);
    k_omp <<<1024, 256, 0, stream>>>(ze, D, G, idxp, valp);
    k_post<<<1536, 256, 0, stream>>>(idxp, valp, coeff, ze, D, zout, accp, lossp);
}

// Round 13
// 193.334 us; speedup vs baseline: 1.2226x; 1.0010x over previous
//
#include <hip/hip_runtime.h>

#define B_TOTAL 32768
#define NATOM   512
#define MDIM    64
#define KS      5

// ---------------------------------------------------------------------------
// K_GRAM: G = D^T D (512 blocks). Zeroes acc[0] (loss) and acc[1] (counter).
// ---------------------------------------------------------------------------
__global__ void k_gram(const float* __restrict__ D, float* __restrict__ G,
                       float* __restrict__ acc) {
    const int i = blockIdx.x;
    const int t = threadIdx.x;
    __shared__ float col[MDIM];
    if (t < MDIM) col[t] = D[t * NATOM + i];
    __syncthreads();
    for (int j = t; j < NATOM; j += 256) {
        float s = 0.f;
#pragma unroll
        for (int m = 0; m < MDIM; ++m) s = fmaf(col[m], D[m * NATOM + j], s);
        G[i * NATOM + j] = s;
    }
    if (i == 0 && t == 0) { acc[0] = 0.f; ((unsigned*)acc)[1] = 0u; }
}

// ---------------------------------------------------------------------------
// K2: fused h_bar GEMM + per-column OMP — R12 VERBATIM (75.7us measured,
// FETCH 9MB: the (hf,c) block->b remap gives coalesced direct-z_e staging).
//   block = (hf, c); b(bb) = (hf<<11) | (bb<<6) | c, bb = w = 0..31
// ---------------------------------------------------------------------------
__launch_bounds__(256, 2)
__global__ void k_omp(const float* __restrict__ ze, const float* __restrict__ D,
                      const float* __restrict__ G, int* __restrict__ idx_out,
                      float* __restrict__ val_out) {
    const int t    = threadIdx.x;
    const int lane = t & 63;
    const int wv   = t >> 6;
    const int cix  = blockIdx.x & 63;      // c (channel) for this block
    const int hf   = blockIdx.x >> 6;      // h&15 for this block
    const int bbase = (hf << 11) | cix;    // b = bbase + bb*64, bb = w

    __shared__ __align__(16) float data_s[32][68];
    __shared__ __align__(16) float stage[4][2048];   // 8KB per wave

    // stage data tile (64 m x 32 bb=w), coalesced: consecutive t -> bb
    {
        const int cbase = cix * 1024 + hf * 32;
#pragma unroll
        for (int r = 0; r < 8; ++r) {
            int id = r * 256 + t;
            int m = id >> 5, bb = id & 31;
            data_s[bb][m] =
                ze[(m >> 1) * 65536 + cbase + ((m & 1) << 9) + bb];
        }
    }
    __syncthreads();

    const float4* __restrict__ D4 = (const float4*)D;
    const float4* __restrict__ G4 = (const float4*)G;

    // ---- phase 1: h_bar accumulators, 8 b x 8 atoms per lane ----
    float4 acc[8][2];
#pragma unroll
    for (int bb = 0; bb < 8; ++bb) {
        acc[bb][0] = make_float4(0.f, 0.f, 0.f, 0.f);
        acc[bb][1] = make_float4(0.f, 0.f, 0.f, 0.f);
    }
    const int bwbase = wv * 8;

#pragma unroll 4
    for (int c = 0; c < 16; ++c) {
        float4 df[4][2];
#pragma unroll
        for (int mm = 0; mm < 4; ++mm) {
            df[mm][0] = D4[(c * 4 + mm) * 128 + lane];
            df[mm][1] = D4[(c * 4 + mm) * 128 + 64 + lane];
        }
#pragma unroll
        for (int bb = 0; bb < 8; ++bb) {
            const float4 dv = *(const float4*)&data_s[bwbase + bb][c * 4];
            const float dm[4] = {dv.x, dv.y, dv.z, dv.w};
#pragma unroll
            for (int mm = 0; mm < 4; ++mm) {
                acc[bb][0].x = fmaf(df[mm][0].x, dm[mm], acc[bb][0].x);
                acc[bb][0].y = fmaf(df[mm][0].y, dm[mm], acc[bb][0].y);
                acc[bb][0].z = fmaf(df[mm][0].z, dm[mm], acc[bb][0].z);
                acc[bb][0].w = fmaf(df[mm][0].w, dm[mm], acc[bb][0].w);
                acc[bb][1].x = fmaf(df[mm][1].x, dm[mm], acc[bb][1].x);
                acc[bb][1].y = fmaf(df[mm][1].y, dm[mm], acc[bb][1].y);
                acc[bb][1].z = fmaf(df[mm][1].z, dm[mm], acc[bb][1].z);
                acc[bb][1].w = fmaf(df[mm][1].w, dm[mm], acc[bb][1].w);
            }
        }
    }

    // ---- re-stage: acc(8b x 8 atoms) -> hb(64 atoms of group's b) ----
    // 2 rounds of 4 b through the 8KB/wave stage (R0 scheme, verbatim).
    const int g = lane >> 3;       // group = b within wave's 8
    const int p = lane & 7;        // lane within group
    float hb[64];
#pragma unroll
    for (int r = 0; r < 2; ++r) {
        __syncthreads();           // round r-1 reads complete before overwrite
#pragma unroll
        for (int q2 = 0; q2 < 4; ++q2) {
            int bb = r * 4 + q2;
            *(float4*)&stage[wv][q2 * 512 + 4 * lane]       = acc[bb][0];
            *(float4*)&stage[wv][q2 * 512 + 256 + 4 * lane] = acc[bb][1];
        }
        __syncthreads();           // writes committed before reads
        if ((g >> 2) == r) {
#pragma unroll
            for (int q = 0; q < 16; ++q) {
                const float4 v =
                    *(const float4*)&stage[wv][(g & 3) * 512 + 32 * q + 4 * p];
                hb[4 * q + 0] = v.x;
                hb[4 * q + 1] = v.y;
                hb[4 * q + 2] = v.z;
                hb[4 * q + 3] = v.w;
            }
        }
    }

    // ---- phase 2: OMP, 8 concurrent b (one per 8-lane group) ----
    float key[64];
#pragma unroll
    for (int e = 0; e < 64; ++e) key[e] = fabsf(hb[e]);

    unsigned msk0 = 0u, msk1 = 0u;
    int   I[KS];
    float xs[KS];
    float gsel[KS];
    float Lm[15];                   // packed lower-tri

#pragma unroll
    for (int k = 0; k < KS; ++k) {
        // --- 4-way ILP argmax over 64 register keys (mask pre-folded -1) ---
        float cv[4]; int ce[4]; float ch[4];
#pragma unroll
        for (int c4 = 0; c4 < 4; ++c4) {
            cv[c4] = key[16 * c4]; ce[c4] = 16 * c4; ch[c4] = hb[16 * c4];
#pragma unroll
            for (int e = 16 * c4 + 1; e < 16 * c4 + 16; ++e) {
                bool gt = key[e] > cv[c4];  // strict > keeps lowest e
                cv[c4] = gt ? key[e] : cv[c4];
                ce[c4] = gt ? e      : ce[c4];
                ch[c4] = gt ? hb[e]  : ch[c4];
            }
        }
        // combine chains in ascending-e order; strict > keeps lower chain
        float bv = cv[0]; int be = ce[0]; float bhb = ch[0];
#pragma unroll
        for (int c4 = 1; c4 < 4; ++c4) {
            bool gt = cv[c4] > bv;
            bv  = gt ? cv[c4] : bv;
            be  = gt ? ce[c4] : be;
            bhb = gt ? ch[c4] : bhb;
        }
        int bn = 32 * (be >> 2) + 4 * p + (be & 3);
        // --- 3-step reduce across the 8-lane group ---
#pragma unroll
        for (int off = 1; off < 8; off <<= 1) {
            float ov  = __shfl_xor(bv, off);
            int   on  = __shfl_xor(bn, off);
            float ohb = __shfl_xor(bhb, off);
            bool take = (ov > bv) || (ov == bv && on < bn);
            bv = take ? ov : bv; bn = take ? on : bn; bhb = take ? ohb : bhb;
        }
        const int nsel = bn;                // group-uniform
        I[k]    = nsel;
        gsel[k] = bhb;                      // = h_bar[nsel] (original), exact

        // mask the selected atom for future scans
        {
            int own  = (nsel >> 2) & 7;
            int esel = ((nsel >> 5) << 2) | (nsel & 3);
            if (p == own) {
                if (esel < 32) msk0 |= 1u << esel;
                else           msk1 |= 1u << (esel - 32);
            }
        }

        // --- Cholesky update of L ---
        if (k > 0) {
            float gk[KS - 1], w[KS - 1];
#pragma unroll
            for (int ti = 0; ti < KS - 1; ++ti)
                if (ti < k) gk[ti] = G[I[ti] * NATOM + nsel];
#pragma unroll
            for (int r = 0; r < KS - 1; ++r) {
                if (r < k) {
                    float s = gk[r];
#pragma unroll
                    for (int cc = 0; cc < KS - 1; ++cc)
                        if (cc < r) s -= Lm[r * (r + 1) / 2 + cc] * w[cc];
                    w[r] = s / Lm[r * (r + 1) / 2 + r];
                }
            }
            float s2 = 0.f;
#pragma unroll
            for (int r = 0; r < KS - 1; ++r) if (r < k) s2 += w[r] * w[r];
            float wc = sqrtf(fmaxf(0.f, 1.f - s2));
#pragma unroll
            for (int cc = 0; cc < KS - 1; ++cc)
                if (cc < k) Lm[k * (k + 1) / 2 + cc] = w[cc];
            Lm[k * (k + 1) / 2 + k] = wc;
        } else {
            Lm[0] = 1.f;
        }

        // --- solve L y = gsel ; L^T x = y (replicated within group) ---
        float y[KS];
#pragma unroll
        for (int r = 0; r <= k; ++r) {
            float s = gsel[r];
#pragma unroll
            for (int cc = 0; cc < r; ++cc) s -= Lm[r * (r + 1) / 2 + cc] * y[cc];
            y[r] = s / Lm[r * (r + 1) / 2 + r];
        }
#pragma unroll
        for (int r = k; r >= 0; --r) {
            float s = y[r];
#pragma unroll
            for (int cc = r + 1; cc <= k; ++cc) s -= Lm[cc * (cc + 1) / 2 + r] * xs[cc];
            xs[r] = s / Lm[r * (r + 1) / 2 + r];
        }

        // --- fused beta + key update (no beta[] array; ascending-ti fma) ---
        if (k < KS - 1) {
#pragma unroll
            for (int q = 0; q < 16; ++q) {
                float bx = 0.f, by = 0.f, bz = 0.f, bw = 0.f;
#pragma unroll
                for (int ti = 0; ti < KS - 1; ++ti) {
                    if (ti <= k) {
                        const float4 gc = G4[I[ti] * 128 + 8 * q + p];
                        bx = fmaf(xs[ti], gc.x, bx);
                        by = fmaf(xs[ti], gc.y, by);
                        bz = fmaf(xs[ti], gc.z, bz);
                        bw = fmaf(xs[ti], gc.w, bw);
                    }
                }
                {
                    float d0 = hb[4 * q + 0] - bx;
                    float d1 = hb[4 * q + 1] - by;
                    float d2 = hb[4 * q + 2] - bz;
                    float d3 = hb[4 * q + 3] - bw;
                    const int e0 = 4 * q;
                    bool m0 = (e0 + 0 < 32) ? ((msk0 >> (e0 + 0)) & 1u) : ((msk1 >> (e0 - 32)) & 1u);
                    bool m1 = (e0 + 1 < 32) ? ((msk0 >> (e0 + 1)) & 1u) : ((msk1 >> (e0 + 1 - 32)) & 1u);
                    bool m2 = (e0 + 2 < 32) ? ((msk0 >> (e0 + 2)) & 1u) : ((msk1 >> (e0 + 2 - 32)) & 1u);
                    bool m3 = (e0 + 3 < 32) ? ((msk0 >> (e0 + 3)) & 1u) : ((msk1 >> (e0 + 3 - 32)) & 1u);
                    key[e0 + 0] = m0 ? -1.f : fabsf(d0);
                    key[e0 + 1] = m1 ? -1.f : fabsf(d1);
                    key[e0 + 2] = m2 ? -1.f : fabsf(d2);
                    key[e0 + 3] = m3 ? -1.f : fabsf(d3);
                }
            }
        }
    }

    // outputs: one lane per b; b = bbase + (wv*8+g)*64 (scattered 4B stores)
    if (p == 0) {
        const int b = bbase + ((wv * 8 + g) << 6);
#pragma unroll
        for (int k = 0; k < KS; ++k) {
            idx_out[k * B_TOTAL + b] = I[k];
            val_out[k * B_TOTAL + b] = xs[k];
        }
    }
}

// ---------------------------------------------------------------------------
// K_POST: fused coeff (blocks 0..1023) + recon (blocks 1024..1535) + loss
// finalize (done-counter, harness-proven R7/R10/R11/R12).
// R12 post-mortem: the c-major recon's direct zp read (consecutive t ->
// consecutive c -> stride-1024) is a 64-line/wave gather x16/thread: ~+27us
// vs R9's dataT recon. Fix WITHOUT dataT: stage the ze tile through LDS
// first (lds[c][i] = ze[..c*1024+hw0+i], consecutive t -> i -> coalesced),
// compute c-major reading lds[c][j] (stride-65 = 2-way bank alias = free,
// m136), store result in-place, then the usual coalesced transpose
// write-out. Every global access in recon is now coalesced; per-thread
// arithmetic identical to R12 (same ownership, same order -> same absmax).
// ---------------------------------------------------------------------------
__global__ void k_post(const int* __restrict__ idx, const float* __restrict__ val,
                       float* __restrict__ coeff, const float* __restrict__ ze,
                       const float* __restrict__ D, float* __restrict__ zout,
                       float* __restrict__ acc, float* __restrict__ out_loss) {
    __shared__ float lds[64][65];
    const int t = threadIdx.x;
    if (blockIdx.x < 1024) {
        const int bblk = blockIdx.x >> 3;
        const int jc   = blockIdx.x & 7;
        const int b    = bblk * 256 + t;
        int   I[KS]; float V[KS];
#pragma unroll
        for (int k = 0; k < KS; ++k) {
            I[k] = idx[k * B_TOTAL + b];
            V[k] = val[k * B_TOTAL + b];
        }
        const int j0 = jc * 64;
#pragma unroll 4
        for (int j = j0; j < j0 + 64; ++j) {
            float w = 0.f;
#pragma unroll
            for (int k = 0; k < KS; ++k) w = (I[k] == j) ? V[k] : w;
            coeff[j * B_TOTAL + b] = w;
        }
    } else {
        const int blk = blockIdx.x - 1024;
        const int n   = blk >> 4;
        const int hw0 = (blk & 15) * 64;

        // stage 1: load ze tile coalesced (row c, consecutive i)
#pragma unroll
        for (int r = 0; r < 16; ++r) {
            int id = r * 256 + t;
            int c = id >> 6, i = id & 63;
            lds[c][i] = ze[n * 65536 + c * 1024 + hw0 + i];
        }
        __syncthreads();

        // stage 2: c-major compute; zp from LDS; in-place result
        float sq = 0.f;
#pragma unroll
        for (int r = 0; r < 16; ++r) {
            int id = r * 256 + t;
            int c = id & 63, j = id >> 6;
            int f = n * 65536 + (hw0 + j) * 64 + c;
            int b = f & 32767;
            int m = f >> 15;
            float zdl = 0.f;
#pragma unroll
            for (int k = 0; k < KS; ++k) {
                int   a = idx[k * B_TOTAL + b];
                float v = val[k * B_TOTAL + b];
                zdl = fmaf(v, D[m * NATOM + a], zdl);
            }
            float zp   = lds[c][j];
            float diff = zdl - zp;
            lds[c][j] = zp + diff;     // in-place: each cell owned by one thread
            sq = fmaf(diff, diff, sq);
        }
        __syncthreads();

        // stage 3: coalesced transpose write-out
#pragma unroll
        for (int r = 0; r < 16; ++r) {
            int id = r * 256 + t;
            int cc = id >> 6, i = id & 63;
            zout[n * 65536 + cc * 1024 + hw0 + i] = lds[cc][i];
        }
#pragma unroll
        for (int off = 32; off > 0; off >>= 1) sq += __shfl_xor(sq, off);
        __shared__ float red[4];
        if ((t & 63) == 0) red[t >> 6] = sq;
        __syncthreads();
        if (t == 0) {
            atomicAdd(acc, red[0] + red[1] + red[2] + red[3]);
            __threadfence();
            unsigned prev = atomicAdd(((unsigned*)acc) + 1, 1u);
            if (prev == 511u) {            // last recon block: all adds visible
                float a = atomicAdd(acc, 0.f);   // device-coherent read
                out_loss[0] = 1.25f * (a / 2097152.f);
            }
        }
    }
}

// ---------------------------------------------------------------------------
extern "C" void kernel_launch(void* const* d_in, const int* in_sizes, int n_in,
                              void* d_out, int out_size, void* d_ws, size_t ws_size,
                              hipStream_t stream) {
    const float* ze = (const float*)d_in[0];
    const float* D  = (const float*)d_in[1];

    float* G     = (float*)d_ws;
    int*   idxp  = (int*)  ((char*)d_ws + (size_t)262144 * 4);
    float* valp  = (float*)((char*)d_ws + (size_t)(262144 + 163840) * 4);
    float* accp  = (float*)((char*)d_ws + (size_t)(262144 + 2 * 163840) * 4);

    float* zout  = (float*)d_out;
    float* lossp = zout + 2097152;
    float* coeff = zout + 2097153;

    k_gram<<< 512, 256, 0, stream>>>(D, G, accp);
    k_omp <<<1024, 256, 0, stream>>>(ze, D, G, idxp, valp);
    k_post<<<1536, 256, 0, stream>>>(idxp, valp, coeff, ze, D, zout, accp, lossp);
}